// Round 7
// baseline (147.514 us; speedup 1.0000x reference)
//
#include <hip/hip_runtime.h>
#include <hip/hip_bf16.h>
#include <math.h>

#define N_ROWS 8192
#define DIM 256
#define NCLS 128
// scale folded into normalized rows: sqrt((1/0.07) * log2(e))
#define ROW_SCALE 4.539816f
#define CLAMP_Y 14.426950408889634f   // 10 * log2(e)
#define LN2F 0.6931471805599453f
#define NBLK 512                      // 32 pairs x 16 chunks, 2 blocks/CU

typedef short bf16x8 __attribute__((ext_vector_type(8)));
typedef float f32x4 __attribute__((ext_vector_type(4)));

#define AS1 __attribute__((address_space(1)))
#define AS3 __attribute__((address_space(3)))

__device__ __forceinline__ void load16_to_lds(const void* g, void* lds) {
  // LDS dest = wave-uniform base + lane*16 (HW rule); gptr is per-lane
  __builtin_amdgcn_global_load_lds((const AS1 void*)g, (AS3 void*)lds, 16, 0, 0);
}

__device__ __forceinline__ unsigned short f2bf(float x) {
  union { __hip_bfloat16 b; unsigned short u; } cv;
  cv.b = __float2bfloat16(x);
  return cv.u;
}

__device__ __forceinline__ float fast_exp2(float x) {
#if __has_builtin(__builtin_amdgcn_exp2f)
  return __builtin_amdgcn_exp2f(x);
#else
  return exp2f(x);
#endif
}

// ---------------- row-normalize*ROW_SCALE -> bf16, zero S/P/done ------------
__global__ __launch_bounds__(256) void normalize_kernel(const float* __restrict__ f,
                                                        unsigned short* __restrict__ fnb,
                                                        float* __restrict__ S,
                                                        float* __restrict__ P,
                                                        unsigned int* __restrict__ done) {
  const int row = blockIdx.x * 4 + (threadIdx.x >> 6);
  const int l = threadIdx.x & 63;
  const float4 v = ((const float4*)(f + (size_t)row * DIM))[l];
  float ss = v.x * v.x + v.y * v.y + v.z * v.z + v.w * v.w;
#pragma unroll
  for (int m = 32; m >= 1; m >>= 1) ss += __shfl_xor(ss, m, 64);
  const float inv = ROW_SCALE / fmaxf(sqrtf(ss), 1e-6f);
  ushort4 o;
  o.x = f2bf(v.x * inv);
  o.y = f2bf(v.y * inv);
  o.z = f2bf(v.z * inv);
  o.w = f2bf(v.w * inv);
  ((ushort4*)(fnb + (size_t)row * DIM))[l] = o;
  if (l == 0) { S[row] = 0.f; P[row] = 0.f; }
  if (blockIdx.x == 0 && threadIdx.x == 0) *done = 0u;
}

// ---------------- triangular GEMM, BK=64 stage->sync->consume ---------------
// R5/R6 lesson: issuing global_load_lds then ds_read-ing the OTHER buffer
// forces a compiler vmcnt(0) before the ds_reads (can't disambiguate the DMA
// target) -> full latency serialization. So: NO loads in flight during
// compute. Barriers amortized by fat BK=64 slices (8 barriers/tile, 32 MFMAs
// per drain). 512 blocks (2/CU, 80 KB LDS): block = (pair, chunk); pair p
// owns rows {p, 63-p} of the 64x64 tile-triangle (65 tiles), chunk = ~4
// tiles. A(bi) LDS-resident, restaged <=1x/block. Off-diag tiles feed row
// sums (regs, flushed per bi-run) AND col sums via symmetry (direct per-quad
// atomics). Diagonal contributes exactly e=1 / y=CLAMP_Y, fixed in finalize.
struct SM {
  unsigned short A[128 * 256];   // 64 KB; rows 512 B, chunk c stored at c^(r&7)
  unsigned short B[128 * 64];    // 16 KB; rows 128 B, slot s holds chunk s^(n&7)
};

__global__ __launch_bounds__(256, 2) void simloss_tri(
    const unsigned short* __restrict__ fnb, const int* __restrict__ labels,
    float* __restrict__ S, float* __restrict__ P,
    unsigned int* __restrict__ done, float* __restrict__ out) {
  __shared__ SM sm;   // exactly 81920 B; finalize scratch aliased inside

  const int tid = threadIdx.x;
  const int w = tid >> 6, l = tid & 63;
  const int wr = w >> 1, wc = w & 1;
  const int ln15 = l & 15, q = l >> 4;

  const int pair = blockIdx.x >> 4;    // 0..31
  const int chunk = blockIdx.x & 15;   // 0..15
  const int rowA = pair, rowB = 63 - pair;
  const int nA = 64 - rowA;            // tiles in first row of the pair
  const int g0 = (65 * chunk) >> 4;
  const int g1 = (65 * (chunk + 1)) >> 4;

  // stage B slice [128 rows][64 K] (16 KB) for tile jbase, super-k sk.
  // LDS rows 128 B; 16B slot s of row n holds source chunk s^(n&7)
  // (ds_read_b128 then lands on all 32 banks per 8 rows; 2-way = free).
  auto stage_B = [&](int jbase, int sk) {
#pragma unroll
    for (int i = 0; i < 4; ++i) {
      const int off = i * 4096 + w * 1024 + l * 16;
      const int row = off >> 7;
      const int c = ((off >> 4) & 7) ^ (row & 7);
      load16_to_lds((const char*)fnb + (size_t)(jbase + row) * 512 +
                        (size_t)sk * 128 + c * 16,
                    (char*)sm.B + i * 4096 + w * 1024);
    }
  };

  float rs[16], rp[16];
  int rowlab[16];
  int cur_bi = -1;

  auto flush_rows = [&]() {
#pragma unroll
    for (int m = 1; m <= 8; m <<= 1)
#pragma unroll
      for (int t = 0; t < 16; ++t) {
        rs[t] += __shfl_xor(rs[t], m, 64);
        rp[t] += __shfl_xor(rp[t], m, 64);
      }
    if (ln15 == 0) {
#pragma unroll
      for (int t = 0; t < 16; ++t) {
        const int rl = cur_bi * 128 + wr * 64 + (t >> 2) * 16 + q * 4 + (t & 3);
        atomicAdd(&S[rl], rs[t]);
        atomicAdd(&P[rl], rp[t]);
      }
    }
  };

  for (int g = g0; g < g1; ++g) {
    int bi, bj;
    if (g < nA) { bi = rowA; bj = rowA + g; }
    else        { bi = rowB; bj = rowB + (g - nA); }
    const int jbase = bj * 128;

    if (bi != cur_bi) {
      if (cur_bi >= 0) flush_rows();
      __syncthreads();  // all waves done reading old A/B before overwrite
      cur_bi = bi;
      const int ibase = bi * 128;
      // stage A [128][256]; 16B chunk c of row r stored at c^(r&7); source
      // addresses per instruction are contiguous 1 KB.
#pragma unroll
      for (int r = 0; r < 16; ++r) {
        const int off = r * 4096 + w * 1024 + l * 16;
        const int row = off >> 9;
        const int c = ((off >> 4) & 31) ^ (row & 7);
        load16_to_lds((const char*)fnb + (size_t)(ibase + row) * 512 + c * 16,
                      (char*)sm.A + r * 4096 + w * 1024);
      }
      __syncthreads();  // A ready (vmcnt fully drained)
#pragma unroll
      for (int mi = 0; mi < 4; ++mi)
#pragma unroll
        for (int rg = 0; rg < 4; ++rg)
          rowlab[mi * 4 + rg] = labels[ibase + wr * 64 + mi * 16 + q * 4 + rg];
#pragma unroll
      for (int t = 0; t < 16; ++t) { rs[t] = 0.f; rp[t] = 0.f; }
    }

    int labJ[4];
#pragma unroll
    for (int ni = 0; ni < 4; ++ni)
      labJ[ni] = labels[jbase + wc * 64 + ni * 16 + ln15];

    f32x4 acc[4][4];
#pragma unroll
    for (int mi = 0; mi < 4; ++mi)
#pragma unroll
      for (int ni = 0; ni < 4; ++ni) acc[mi][ni] = (f32x4)0.0f;

#pragma unroll
    for (int sk = 0; sk < 4; ++sk) {
      __syncthreads();          // previous B slice fully consumed
      stage_B(jbase, sk);
      __syncthreads();          // B slice resident; NOTHING left in flight
#pragma unroll
      for (int kt2 = 0; kt2 < 2; ++kt2) {
        const int kt = sk * 2 + kt2;
        bf16x8 af[4], bfr[4];
#pragma unroll
        for (int mi = 0; mi < 4; ++mi) {
          const int row = wr * 64 + mi * 16 + ln15;
          const int c = (kt * 4 + q) ^ (row & 7);
          af[mi] = *(const bf16x8*)((const char*)sm.A + row * 512 + c * 16);
        }
#pragma unroll
        for (int ni = 0; ni < 4; ++ni) {
          const int n = wc * 64 + ni * 16 + ln15;
          const int c = (kt2 * 4 + q) ^ (n & 7);
          bfr[ni] = *(const bf16x8*)((const char*)sm.B + n * 128 + c * 16);
        }
#pragma unroll
        for (int mi = 0; mi < 4; ++mi)
#pragma unroll
          for (int ni = 0; ni < 4; ++ni)
            acc[mi][ni] = __builtin_amdgcn_mfma_f32_16x16x32_bf16(
                af[mi], bfr[ni], acc[mi][ni], 0, 0, 0);
      }
    }

    // ---- epilogue: exp-sum + positive-sim (rows persist; cols via symmetry)
    float cs[4], cp[4];
#pragma unroll
    for (int t = 0; t < 4; ++t) { cs[t] = 0.f; cp[t] = 0.f; }
#pragma unroll
    for (int mi = 0; mi < 4; ++mi)
#pragma unroll
      for (int ni = 0; ni < 4; ++ni)
#pragma unroll
        for (int rg = 0; rg < 4; ++rg) {
          const float y = acc[mi][ni][rg];
          const float yc = fminf(CLAMP_Y, fmaxf(-CLAMP_Y, y));  // v_med3
          const float e = fast_exp2(yc - CLAMP_Y);
          const float pv = (labJ[ni] == rowlab[mi * 4 + rg]) ? yc : 0.0f;
          rs[mi * 4 + rg] += e;
          rp[mi * 4 + rg] += pv;
          cs[ni] += e;
          cp[ni] += pv;
        }

    if (bj != bi) {  // col sums -> rows of bj; both wr-waves add partials
#pragma unroll
      for (int m = 16; m <= 32; m <<= 1)
#pragma unroll
        for (int t = 0; t < 4; ++t) {
          cs[t] += __shfl_xor(cs[t], m, 64);
          cp[t] += __shfl_xor(cp[t], m, 64);
        }
      if (q == 0) {
#pragma unroll
        for (int ni = 0; ni < 4; ++ni) {
          const int col = jbase + wc * 64 + ni * 16 + ln15;
          atomicAdd(&S[col], cs[ni]);
          atomicAdd(&P[col], cp[ni]);
        }
      }
    }
  }
  flush_rows();

  // ---- completion: last block performs the finalize (scratch aliased in sm)
  unsigned int* lastflag = (unsigned int*)sm.B;
  __threadfence();
  __syncthreads();
  if (tid == 0) {
    const unsigned int old = __hip_atomic_fetch_add(done, 1u, __ATOMIC_ACQ_REL,
                                                    __HIP_MEMORY_SCOPE_AGENT);
    *lastflag = (old == NBLK - 1) ? 1u : 0u;
  }
  __syncthreads();
  if (*lastflag) {
    int* h = (int*)sm.A;                 // label histogram
    float* ls = (float*)sm.B + 64;       // wave partials (clear of lastflag)
    float* vs = ls + 8;
    if (tid < NCLS) h[tid] = 0;
    __syncthreads();
    for (int i = tid; i < N_ROWS; i += 256) atomicAdd(&h[labels[i]], 1);
    __syncthreads();
    float lsum = 0.f, vsum = 0.f;
    for (int i = tid; i < N_ROWS; i += 256) {
      const int cnt = h[labels[i]] - 1;  // positives excluding self
      if (cnt > 0) {
        const float s = __hip_atomic_load(&S[i], __ATOMIC_RELAXED,
                                          __HIP_MEMORY_SCOPE_AGENT);
        const float p = __hip_atomic_load(&P[i], __ATOMIC_RELAXED,
                                          __HIP_MEMORY_SCOPE_AGENT);
        const float lse = 10.0f + logf(s - 1.0f);   // remove diag e=1
        const float psum = p * LN2F - 10.0f;        // de-scale, remove diag
        lsum += lse - psum / (float)cnt;            // -mean_log_prob_pos
        vsum += 1.0f;
      }
    }
#pragma unroll
    for (int m = 32; m >= 1; m >>= 1) {
      lsum += __shfl_xor(lsum, m, 64);
      vsum += __shfl_xor(vsum, m, 64);
    }
    if (l == 0) { ls[w] = lsum; vs[w] = vsum; }
    __syncthreads();
    if (tid == 0) {
      float L = 0.f, V = 0.f;
      for (int k = 0; k < 4; ++k) { L += ls[k]; V += vs[k]; }
      out[0] = (V > 0.f) ? (L / fmaxf(V, 1.0f)) : 0.f;
    }
  }
}

extern "C" void kernel_launch(void* const* d_in, const int* in_sizes, int n_in,
                              void* d_out, int out_size, void* d_ws, size_t ws_size,
                              hipStream_t stream) {
  const float* feat = (const float*)d_in[0];
  const int* labels = (const int*)d_in[1];
  float* out = (float*)d_out;

  char* ws = (char*)d_ws;
  unsigned short* fnb = (unsigned short*)ws;            // bf16 [8192][256], 4 MB
  float* S = (float*)(ws + (size_t)N_ROWS * DIM * 2);   // [8192]
  float* P = S + N_ROWS;                                // [8192]
  unsigned int* done = (unsigned int*)(P + N_ROWS);     // [1]

  normalize_kernel<<<N_ROWS / 4, 256, 0, stream>>>(feat, fnb, S, P, done);
  simloss_tri<<<NBLK, 256, 0, stream>>>(fnb, labels, S, P, done, out);
}